// Round 15
// baseline (481.566 us; speedup 1.0000x reference)
//
#include <hip/hip_runtime.h>
#include <hip/hip_bf16.h>

#define NTOK 512
#define HDIM 2880
#define NGU  5760
#define NEXP 16
#define KSTEPS 90   // 2880 / 32
#define KSH   45    // K-steps per half (down kernel)
#define MT 160      // m-tile rows (covers n_e up to 160 in one tile)
#define MFR 10      // MT/16 m-fragments
#define NPAIR (NTOK*4)
#define PARTELT ((size_t)NPAIR * HDIM)   // elements per bf16 partial buffer

typedef float  f32x4  __attribute__((ext_vector_type(4)));
typedef float  f32x2  __attribute__((ext_vector_type(2)));
typedef short  bf16x8 __attribute__((ext_vector_type(8)));

__device__ __forceinline__ unsigned short f2bf(float f) {
  union { float f; unsigned u; } a; a.f = f;
  unsigned r = a.u + 0x7FFFu + ((a.u >> 16) & 1u);   // RNE truncate to bf16
  return (unsigned short)(r >> 16);
}
__device__ __forceinline__ float bflo(unsigned u) {
  union { unsigned u; float f; } c; c.u = u << 16; return c.f;
}
__device__ __forceinline__ float bfhi(unsigned u) {
  union { unsigned u; float f; } c; c.u = u & 0xffff0000u; return c.f;
}

// Barrier that does NOT drain vmcnt: LDS-only wait + raw s_barrier.
__device__ __forceinline__ void lds_barrier() {
  asm volatile("s_waitcnt lgkmcnt(0)" ::: "memory");
  __builtin_amdgcn_s_barrier();
  asm volatile("" ::: "memory");
}

// ---------------- control kernels ----------------

// router + x->bf16 conversion fused (x is read here anyway)
__global__ __launch_bounds__(256) void k_router(
    const float* __restrict__ x, const float* __restrict__ rw,
    const float* __restrict__ rb, int* __restrict__ counts,
    int* __restrict__ top_e, float* __restrict__ top_w,
    unsigned short* __restrict__ xb)
{
  const int t = blockIdx.x;
  const int tid = threadIdx.x;
  __shared__ float red[256][17];
  float acc[NEXP];
#pragma unroll
  for (int e = 0; e < NEXP; ++e) acc[e] = 0.f;
  const float* xr = x + (size_t)t * HDIM;
  unsigned short* xbr = xb + (size_t)t * HDIM;
  for (int h = tid; h < HDIM; h += 256) {
    float xv = xr[h];
    xbr[h] = f2bf(xv);
    const f32x4* wr = (const f32x4*)(rw + (size_t)h * NEXP);
#pragma unroll
    for (int q = 0; q < 4; ++q) {
      f32x4 w = wr[q];
#pragma unroll
      for (int j = 0; j < 4; ++j) acc[q*4+j] += xv * w[j];
    }
  }
#pragma unroll
  for (int e = 0; e < NEXP; ++e) red[tid][e] = acc[e];
  __syncthreads();
  for (int s = 128; s > 0; s >>= 1) {
    if (tid < s) {
#pragma unroll
      for (int e = 0; e < NEXP; ++e) red[tid][e] += red[tid + s][e];
    }
    __syncthreads();
  }
  if (tid == 0) {
    float v[NEXP];
#pragma unroll
    for (int e = 0; e < NEXP; ++e) v[e] = red[0][e] + rb[e];
    int mask = 0; float tv[4]; int ti[4];
    for (int k = 0; k < 4; ++k) {
      float best = -3.4e38f; int bi = 0;
      for (int e = 0; e < NEXP; ++e)
        if (!((mask >> e) & 1) && v[e] > best) { best = v[e]; bi = e; }
      mask |= 1 << bi; tv[k] = best; ti[k] = bi;
    }
    float s = 0.f, ex[4];
    for (int k = 0; k < 4; ++k) { ex[k] = __expf(tv[k] - tv[0]); s += ex[k]; }
    float inv = 1.f / s;
    for (int k = 0; k < 4; ++k) {
      top_e[t*4+k] = ti[k];
      top_w[t*4+k] = ex[k] * inv;
      atomicAdd(&counts[ti[k]], 1);
    }
  }
}

// one wave per expert; deterministic compaction; prefix-scan folded in.
__global__ __launch_bounds__(64) void k_fill(
    const int* __restrict__ top_e, const float* __restrict__ top_w,
    const int* __restrict__ counts, int* __restrict__ seg,
    int* __restrict__ pair_tok, float* __restrict__ pair_w,
    int* __restrict__ pair_of)
{
  const int e = blockIdx.x;
  const int lane = threadIdx.x;
  int base = 0;
  for (int i = 0; i < e; ++i) base += counts[i];
  if (lane == 0) {
    seg[e] = base;
    if (e == NEXP - 1) seg[NEXP] = base + counts[e];
  }
  for (int t0 = 0; t0 < NTOK; t0 += 64) {
    int t = t0 + lane;
    int my = -1;
#pragma unroll
    for (int k = 0; k < 4; ++k) if (top_e[t*4+k] == e) my = k;
    unsigned long long m = __ballot(my >= 0);
    if (my >= 0) {
      int pre = __popcll(m & ((1ull << lane) - 1ull));
      pair_tok[base + pre] = t;
      pair_w[base + pre] = top_w[t*4+my];
      pair_of[t*4 + my] = base + pre;
    }
    base += (int)__popcll(m);
  }
}

// ---------------- gate_up: B staged via LDS (1KB-contiguous wave loads) ----
// Experiment: per staging instruction, one wave reads ONE full weight row
// segment of 1KB contiguously (m13's max-BW pattern) instead of 4x256B on
// 4 rows. B panel (32k x 256col f32 -> bf16) double-buffered in LDS;
// fragments via ds_read_b64.
__global__ __launch_bounds__(256, 2) void k_gateup(
    const unsigned short* __restrict__ xb, const float* __restrict__ gw,
    const float* __restrict__ gb, const int* __restrict__ seg,
    const int* __restrict__ pair_tok, const float* __restrict__ pair_w,
    unsigned short* __restrict__ act)
{
  const int e = blockIdx.z;
  const int segs = seg[e];
  const int n_e = seg[e+1] - segs;
  const int m0 = blockIdx.y * MT;
  if (m0 >= n_e) return;
  const int tid = threadIdx.x;
  const int lane = tid & 63;
  const int wid = tid >> 6;
  const int l15 = lane & 15, lg = lane >> 4;
  const int fcb = blockIdx.x * 128 + wid * 32;
  const int fcE = fcb + 2*l15;
  const int colf = min(2*fcb + 4*l15, NGU - 4);   // bias load only
  const int cloc = wid*64 + 4*l15;                // local col in B panel

  __shared__ unsigned short Alds[2][MT][40];
  __shared__ unsigned short Blds[2][32][256];

  const float* We = gw + (size_t)e * HDIM * NGU;
  const int colbase = blockIdx.x * 256;
  const int srow = tid >> 6;            // wave id: row offset within round
  const int scol = (tid & 63) * 4;      // f32 col within panel
  const int gcol = min(colbase + scol, NGU - 4);

  const unsigned short* sp0 = nullptr;
  const unsigned short* sp1 = nullptr;
  const int r0 = tid >> 1, h0 = tid & 1;
  const int r1 = (tid + 256) >> 1, h1 = tid & 1;
  if (m0 + r0 < n_e) sp0 = xb + (size_t)pair_tok[segs + m0 + r0] * HDIM + h0*16;
  if (tid < 2*MT - 256 && m0 + r1 < n_e)
    sp1 = xb + (size_t)pair_tok[segs + m0 + r1] * HDIM + h1*16;

  f32x4 accgE[MFR], accuE[MFR], accgO[MFR], accuO[MFR];
  {
    f32x4 b = __builtin_nontemporal_load((const f32x4*)(gb + (size_t)e * NGU + colf));
#pragma unroll
    for (int m = 0; m < MFR; ++m)
#pragma unroll
      for (int r = 0; r < 4; ++r) {
        accgE[m][r] = b[0]; accuE[m][r] = b[1];
        accgO[m][r] = b[2]; accuO[m][r] = b[3];
      }
  }

  auto stage = [&](int ks, int b) {
    bf16x8 z = {0,0,0,0,0,0,0,0};
    bf16x8 v0 = z, v1 = z;
    if (sp0) { v0 = *(const bf16x8*)(sp0 + ks*32); v1 = *(const bf16x8*)(sp0 + ks*32 + 8); }
    *(bf16x8*)&Alds[b][r0][h0*16]     = v0;
    *(bf16x8*)&Alds[b][r0][h0*16 + 8] = v1;
    if (tid < 2*MT - 256) {
      bf16x8 w0 = z, w1 = z;
      if (sp1) { w0 = *(const bf16x8*)(sp1 + ks*32); w1 = *(const bf16x8*)(sp1 + ks*32 + 8); }
      *(bf16x8*)&Alds[b][r1][h1*16]     = w0;
      *(bf16x8*)&Alds[b][r1][h1*16 + 8] = w1;
    }
  };

  f32x4 sreg[8];
  auto loadBq = [&](int ks) {
#pragma unroll
    for (int q = 0; q < 8; ++q) {
      const float* p = We + (size_t)(ks*32 + q*4 + srow) * NGU + gcol;
      sreg[q] = __builtin_nontemporal_load((const f32x4*)p);
    }
  };
  auto writeB = [&](int b) {
#pragma unroll
    for (int q = 0; q < 8; ++q) {
      ushort4 o;
      o.x = f2bf(sreg[q][0]); o.y = f2bf(sreg[q][1]);
      o.z = f2bf(sreg[q][2]); o.w = f2bf(sreg[q][3]);
      *(ushort4*)&Blds[b][q*4 + srow][scol] = o;
    }
  };

  loadBq(0);
  stage(0, 0);
  writeB(0);
  lds_barrier();
  int buf = 0;

  for (int ks = 0; ks < KSTEPS; ++ks) {
    if (ks + 1 < KSTEPS) { loadBq(ks + 1); stage(ks + 1, buf ^ 1); }
    // B fragments from LDS: one ds_read_b64 per k-element j
    ushort4 v[8];
#pragma unroll
    for (int j = 0; j < 8; ++j)
      v[j] = *(const ushort4*)&Blds[buf][lg*8 + j][cloc];
    bf16x8 bgE, buE, bgO, buO;
#pragma unroll
    for (int j = 0; j < 8; ++j) {
      bgE[j] = (short)v[j].x; buE[j] = (short)v[j].y;
      bgO[j] = (short)v[j].z; buO[j] = (short)v[j].w;
    }
#pragma unroll
    for (int m = 0; m < MFR; ++m) {
      bf16x8 a = *(const bf16x8*)&Alds[buf][m*16 + l15][lg*8];
      accgE[m] = __builtin_amdgcn_mfma_f32_16x16x32_bf16(a, bgE, accgE[m], 0, 0, 0);
      accuE[m] = __builtin_amdgcn_mfma_f32_16x16x32_bf16(a, buE, accuE[m], 0, 0, 0);
      accgO[m] = __builtin_amdgcn_mfma_f32_16x16x32_bf16(a, bgO, accgO[m], 0, 0, 0);
      accuO[m] = __builtin_amdgcn_mfma_f32_16x16x32_bf16(a, buO, accuO[m], 0, 0, 0);
    }
    if (ks + 1 < KSTEPS) writeB(buf ^ 1);
    lds_barrier();
    buf ^= 1;
  }

  if (fcE < HDIM) {
#pragma unroll
    for (int m = 0; m < MFR; ++m) {
#pragma unroll
      for (int r = 0; r < 4; ++r) {
        int grow = m0 + m*16 + lg*4 + r;
        if (grow < n_e) {
          float pw = pair_w[segs + grow];
          float gE = fminf(accgE[m][r], 7.f);
          float uE = fminf(fmaxf(accuE[m][r], -7.f), 7.f);
          float avE = (uE + 1.f) * (gE / (1.f + __expf(-1.702f * gE))) * pw;
          float gO = fminf(accgO[m][r], 7.f);
          float uO = fminf(fmaxf(accuO[m][r], -7.f), 7.f);
          float avO = (uO + 1.f) * (gO / (1.f + __expf(-1.702f * gO))) * pw;
          unsigned pk = (unsigned)f2bf(avE) | ((unsigned)f2bf(avO) << 16);
          *(unsigned*)&act[(size_t)(segs + grow) * HDIM + fcE] = pk;
        }
      }
    }
  }
}

// ---------------- down projection: K-split halves, bf16 partials ----------
__global__ __launch_bounds__(256, 3) void k_down(
    const unsigned short* __restrict__ act, const float* __restrict__ dw,
    const int* __restrict__ seg, const int* __restrict__ pair_tok,
    unsigned short* __restrict__ partial)
{
  const int e = blockIdx.z;
  const int mi = blockIdx.y >> 1;
  const int kh = blockIdx.y & 1;
  const int segs = seg[e];
  const int n_e = seg[e+1] - segs;
  const int m0 = mi * MT;
  if (m0 >= n_e) return;
  const int tid = threadIdx.x;
  const int lane = tid & 63;
  const int wid = tid >> 6;
  const int l15 = lane & 15, lg = lane >> 4;
  const int cb = blockIdx.x * 128 + wid * 32;
  const int cE = cb + 2*l15;
  const int colc = min(cE, HDIM - 2);
  const int k0 = kh * (KSH * 32);

  __shared__ unsigned short Alds[2][MT][40];

  unsigned short* po = partial + (size_t)kh * PARTELT;
  const float* Bq = dw + (size_t)e * HDIM * HDIM + colc
                  + (size_t)(k0 + lg * 8) * HDIM;

  const unsigned short* sp0 = nullptr;
  const unsigned short* sp1 = nullptr;
  const int r0 = tid >> 1, h0 = tid & 1;
  const int r1 = (tid + 256) >> 1, h1 = tid & 1;
  if (m0 + r0 < n_e) sp0 = act + (size_t)(segs + m0 + r0) * HDIM + k0 + h0*16;
  if (tid < 2*MT - 256 && m0 + r1 < n_e)
    sp1 = act + (size_t)(segs + m0 + r1) * HDIM + k0 + h1*16;

  f32x4 accE[MFR], accO[MFR];
#pragma unroll
  for (int m = 0; m < MFR; ++m)
#pragma unroll
    for (int r = 0; r < 4; ++r) { accE[m][r] = 0.f; accO[m][r] = 0.f; }

  auto stage = [&](int ks, int b) {
    bf16x8 z = {0,0,0,0,0,0,0,0};
    bf16x8 v0 = z, v1 = z;
    if (sp0) { v0 = *(const bf16x8*)(sp0 + ks*32); v1 = *(const bf16x8*)(sp0 + ks*32 + 8); }
    *(bf16x8*)&Alds[b][r0][h0*16]     = v0;
    *(bf16x8*)&Alds[b][r0][h0*16 + 8] = v1;
    if (tid < 2*MT - 256) {
      bf16x8 w0 = z, w1 = z;
      if (sp1) { w0 = *(const bf16x8*)(sp1 + ks*32); w1 = *(const bf16x8*)(sp1 + ks*32 + 8); }
      *(bf16x8*)&Alds[b][r1][h1*16]     = w0;
      *(bf16x8*)&Alds[b][r1][h1*16 + 8] = w1;
    }
  };

  f32x2 bA[8];
  auto loadB = [&](int ks) {
    const float* bp = Bq + (size_t)ks * 32 * HDIM;
#pragma unroll
    for (int j = 0; j < 8; ++j)
      bA[j] = __builtin_nontemporal_load((const f32x2*)(bp + (size_t)j * HDIM));
  };

  loadB(0);
  stage(0, 0);
  lds_barrier();
  int buf = 0;

  for (int ks = 0; ks < KSH; ++ks) {
    if (ks + 1 < KSH) stage(ks + 1, buf ^ 1);
    bf16x8 bfE, bfO;
#pragma unroll
    for (int j = 0; j < 8; ++j) { bfE[j] = (short)f2bf(bA[j][0]); bfO[j] = (short)f2bf(bA[j][1]); }
    if (ks + 1 < KSH) loadB(ks + 1);
#pragma unroll
    for (int m = 0; m < MFR; ++m) {
      bf16x8 a = *(const bf16x8*)&Alds[buf][m*16 + l15][lg*8];
      accE[m] = __builtin_amdgcn_mfma_f32_16x16x32_bf16(a, bfE, accE[m], 0, 0, 0);
      accO[m] = __builtin_amdgcn_mfma_f32_16x16x32_bf16(a, bfO, accO[m], 0, 0, 0);
    }
    lds_barrier();
    buf ^= 1;
  }

  if (cE < HDIM) {
#pragma unroll
    for (int m = 0; m < MFR; ++m) {
#pragma unroll
      for (int r = 0; r < 4; ++r) {
        int grow = m0 + m*16 + lg*4 + r;
        if (grow < n_e) {
          unsigned pk = (unsigned)f2bf(accE[m][r]) | ((unsigned)f2bf(accO[m][r]) << 16);
          *(unsigned*)&po[(size_t)(segs + grow) * HDIM + cE] = pk;
        }
      }
    }
  }
}

// ---- gather: out[t] = sum over 8 bf16 partial rows + score-weighted bias ----
__global__ __launch_bounds__(256) void k_gather(
    const unsigned short* __restrict__ partial, const int* __restrict__ pair_of,
    const int* __restrict__ top_e, const float* __restrict__ top_w,
    const float* __restrict__ db, float* __restrict__ out)
{
  const int t = blockIdx.x;
  const int tid = threadIdx.x;
  const int p0 = pair_of[t*4+0], p1 = pair_of[t*4+1];
  const int p2 = pair_of[t*4+2], p3 = pair_of[t*4+3];
  const float w0 = top_w[t*4+0], w1 = top_w[t*4+1];
  const float w2 = top_w[t*4+2], w3 = top_w[t*4+3];
  const unsigned short* r[8] = {
    partial + (size_t)p0 * HDIM,           partial + (size_t)p1 * HDIM,
    partial + (size_t)p2 * HDIM,           partial + (size_t)p3 * HDIM,
    partial + PARTELT + (size_t)p0 * HDIM, partial + PARTELT + (size_t)p1 * HDIM,
    partial + PARTELT + (size_t)p2 * HDIM, partial + PARTELT + (size_t)p3 * HDIM };
  const float* b0 = db + (size_t)top_e[t*4+0] * HDIM;
  const float* b1 = db + (size_t)top_e[t*4+1] * HDIM;
  const float* b2 = db + (size_t)top_e[t*4+2] * HDIM;
  const float* b3 = db + (size_t)top_e[t*4+3] * HDIM;
  float* o = out + (size_t)t * HDIM;
  for (int p = tid; p < HDIM/4; p += 256) {
    f32x4 s;
    {
      f32x4 c0 = *(const f32x4*)(b0 + 4*p);
      f32x4 c1 = *(const f32x4*)(b1 + 4*p);
      f32x4 c2 = *(const f32x4*)(b2 + 4*p);
      f32x4 c3 = *(const f32x4*)(b3 + 4*p);
#pragma unroll
      for (int j = 0; j < 4; ++j)
        s[j] = (w0*c0[j] + w1*c1[j]) + (w2*c2[j] + w3*c3[j]);
    }
#pragma unroll
    for (int q = 0; q < 8; ++q) {
      uint2 v = *(const uint2*)(r[q] + 4*p);   // 4 bf16: cols 4p..4p+3
      s[0] += bflo(v.x); s[1] += bfhi(v.x);
      s[2] += bflo(v.y); s[3] += bfhi(v.y);
    }
    *(f32x4*)(o + 4*p) = s;
  }
}

// ---------------- launch ----------------

extern "C" void kernel_launch(void* const* d_in, const int* in_sizes, int n_in,
                              void* d_out, int out_size, void* d_ws, size_t ws_size,
                              hipStream_t stream) {
  const float* x  = (const float*)d_in[0];
  const float* rw = (const float*)d_in[1];
  const float* rb = (const float*)d_in[2];
  const float* gw = (const float*)d_in[3];
  const float* gb = (const float*)d_in[4];
  const float* dw = (const float*)d_in[5];
  const float* db = (const float*)d_in[6];
  float* out = (float*)d_out;

  char* w = (char*)d_ws;
  int*   counts   = (int*)(w);
  int*   seg      = (int*)(w + 64);
  int*   top_e    = (int*)(w + 1024);
  float* top_w    = (float*)(w + 1024 + 8192);
  int*   pair_tok = (int*)(w + 1024 + 16384);
  float* pair_w   = (float*)(w + 1024 + 24576);
  int*   pair_of  = (int*)(w + 1024 + 32768);
  unsigned short* xb  = (unsigned short*)(w + (1 << 20));    // 512 x 2880 bf16
  unsigned short* act = (unsigned short*)(w + (8 << 20));    // 2048 x 2880 bf16
  unsigned short* partial = (unsigned short*)(w + (24ull << 20)); // 2 x 2048 x 2880 bf16

  hipMemsetAsync(counts, 0, NEXP * sizeof(int), stream);
  k_router<<<NTOK, 256, 0, stream>>>(x, rw, rb, counts, top_e, top_w, xb);
  k_fill<<<NEXP, 64, 0, stream>>>(top_e, top_w, counts, seg, pair_tok, pair_w, pair_of);

  dim3 gg(23, 2, NEXP);   // 23 fc tiles x {main, overflow} x experts
  k_gateup<<<gg, 256, 0, stream>>>(xb, gw, gb, seg, pair_tok, pair_w, act);

  dim3 gd(23, 4, NEXP);   // 23 col tiles x {m-tile, K-half} x experts
  k_down<<<gd, 256, 0, stream>>>(act, dw, seg, pair_tok, partial);

  k_gather<<<NTOK, 256, 0, stream>>>(partial, pair_of, top_e, top_w, db, out);
}

// Round 16
// 428.741 us; speedup vs baseline: 1.1232x; 1.1232x over previous
//
#include <hip/hip_runtime.h>
#include <hip/hip_bf16.h>

#define NTOK 512
#define HDIM 2880
#define NGU  5760
#define NEXP 16
#define KSTEPS 90   // 2880 / 32
#define KSH   45    // K-steps per half (down kernel)
#define MT 160      // m-tile rows (covers n_e up to 160 in one tile)
#define MFR 10      // MT/16 m-fragments
#define NPAIR (NTOK*4)
#define PARTELT ((size_t)NPAIR * HDIM)   // elements per bf16 partial buffer

typedef float  f32x4  __attribute__((ext_vector_type(4)));
typedef float  f32x2  __attribute__((ext_vector_type(2)));
typedef short  bf16x8 __attribute__((ext_vector_type(8)));

__device__ __forceinline__ unsigned short f2bf(float f) {
  union { float f; unsigned u; } a; a.f = f;
  unsigned r = a.u + 0x7FFFu + ((a.u >> 16) & 1u);   // RNE truncate to bf16
  return (unsigned short)(r >> 16);
}
__device__ __forceinline__ float bflo(unsigned u) {
  union { unsigned u; float f; } c; c.u = u << 16; return c.f;
}
__device__ __forceinline__ float bfhi(unsigned u) {
  union { unsigned u; float f; } c; c.u = u & 0xffff0000u; return c.f;
}

// Barrier that does NOT drain vmcnt: LDS-only wait + raw s_barrier.
__device__ __forceinline__ void lds_barrier() {
  asm volatile("s_waitcnt lgkmcnt(0)" ::: "memory");
  __builtin_amdgcn_s_barrier();
  asm volatile("" ::: "memory");
}

// ---------------- control kernels ----------------

// router + x->bf16 conversion fused (x is read here anyway)
__global__ __launch_bounds__(256) void k_router(
    const float* __restrict__ x, const float* __restrict__ rw,
    const float* __restrict__ rb, int* __restrict__ counts,
    int* __restrict__ top_e, float* __restrict__ top_w,
    unsigned short* __restrict__ xb)
{
  const int t = blockIdx.x;
  const int tid = threadIdx.x;
  __shared__ float red[256][17];
  float acc[NEXP];
#pragma unroll
  for (int e = 0; e < NEXP; ++e) acc[e] = 0.f;
  const float* xr = x + (size_t)t * HDIM;
  unsigned short* xbr = xb + (size_t)t * HDIM;
  for (int h = tid; h < HDIM; h += 256) {
    float xv = xr[h];
    xbr[h] = f2bf(xv);
    const f32x4* wr = (const f32x4*)(rw + (size_t)h * NEXP);
#pragma unroll
    for (int q = 0; q < 4; ++q) {
      f32x4 w = wr[q];
#pragma unroll
      for (int j = 0; j < 4; ++j) acc[q*4+j] += xv * w[j];
    }
  }
#pragma unroll
  for (int e = 0; e < NEXP; ++e) red[tid][e] = acc[e];
  __syncthreads();
  for (int s = 128; s > 0; s >>= 1) {
    if (tid < s) {
#pragma unroll
      for (int e = 0; e < NEXP; ++e) red[tid][e] += red[tid + s][e];
    }
    __syncthreads();
  }
  if (tid == 0) {
    float v[NEXP];
#pragma unroll
    for (int e = 0; e < NEXP; ++e) v[e] = red[0][e] + rb[e];
    int mask = 0; float tv[4]; int ti[4];
    for (int k = 0; k < 4; ++k) {
      float best = -3.4e38f; int bi = 0;
      for (int e = 0; e < NEXP; ++e)
        if (!((mask >> e) & 1) && v[e] > best) { best = v[e]; bi = e; }
      mask |= 1 << bi; tv[k] = best; ti[k] = bi;
    }
    float s = 0.f, ex[4];
    for (int k = 0; k < 4; ++k) { ex[k] = __expf(tv[k] - tv[0]); s += ex[k]; }
    float inv = 1.f / s;
    for (int k = 0; k < 4; ++k) {
      top_e[t*4+k] = ti[k];
      top_w[t*4+k] = ex[k] * inv;
      atomicAdd(&counts[ti[k]], 1);
    }
  }
}

// one wave per expert; deterministic compaction; prefix-scan folded in.
// pair_of[t*4+k] = compacted row index of (token t, slot k) — inverse map.
__global__ __launch_bounds__(64) void k_fill(
    const int* __restrict__ top_e, const float* __restrict__ top_w,
    const int* __restrict__ counts, int* __restrict__ seg,
    int* __restrict__ pair_tok, float* __restrict__ pair_w,
    int* __restrict__ pair_of)
{
  const int e = blockIdx.x;
  const int lane = threadIdx.x;
  int base = 0;
  for (int i = 0; i < e; ++i) base += counts[i];
  if (lane == 0) {
    seg[e] = base;
    if (e == NEXP - 1) seg[NEXP] = base + counts[e];
  }
  for (int t0 = 0; t0 < NTOK; t0 += 64) {
    int t = t0 + lane;
    int my = -1;
#pragma unroll
    for (int k = 0; k < 4; ++k) if (top_e[t*4+k] == e) my = k;
    unsigned long long m = __ballot(my >= 0);
    if (my >= 0) {
      int pre = __popcll(m & ((1ull << lane) - 1ull));
      pair_tok[base + pre] = t;
      pair_w[base + pre] = top_w[t*4+my];
      pair_of[t*4 + my] = base + pre;
    }
    base += (int)__popcll(m);
  }
}

// ---------------- gate_up + activation ----------------
__global__ __launch_bounds__(256, 2) void k_gateup(
    const unsigned short* __restrict__ xb, const float* __restrict__ gw,
    const float* __restrict__ gb, const int* __restrict__ seg,
    const int* __restrict__ pair_tok, const float* __restrict__ pair_w,
    unsigned short* __restrict__ act)
{
  const int e = blockIdx.z;
  const int segs = seg[e];
  const int n_e = seg[e+1] - segs;
  const int m0 = blockIdx.y * MT;
  if (m0 >= n_e) return;
  const int tid = threadIdx.x;
  const int lane = tid & 63;
  const int wid = tid >> 6;
  const int l15 = lane & 15, lg = lane >> 4;
  const int fcb = blockIdx.x * 128 + wid * 32;
  const int fcE = fcb + 2*l15;
  const int colf = min(2*fcb + 4*l15, NGU - 4);

  __shared__ unsigned short Alds[2][MT][40];

  const float* Bq = gw + (size_t)e * HDIM * NGU + colf + (size_t)lg * 8 * NGU;

  const unsigned short* sp0 = nullptr;
  const unsigned short* sp1 = nullptr;
  const int r0 = tid >> 1, h0 = tid & 1;
  const int r1 = (tid + 256) >> 1, h1 = tid & 1;
  if (m0 + r0 < n_e) sp0 = xb + (size_t)pair_tok[segs + m0 + r0] * HDIM + h0*16;
  if (tid < 2*MT - 256 && m0 + r1 < n_e)
    sp1 = xb + (size_t)pair_tok[segs + m0 + r1] * HDIM + h1*16;

  f32x4 accgE[MFR], accuE[MFR], accgO[MFR], accuO[MFR];
  {
    f32x4 b = __builtin_nontemporal_load((const f32x4*)(gb + (size_t)e * NGU + colf));
#pragma unroll
    for (int m = 0; m < MFR; ++m)
#pragma unroll
      for (int r = 0; r < 4; ++r) {
        accgE[m][r] = b[0]; accuE[m][r] = b[1];
        accgO[m][r] = b[2]; accuO[m][r] = b[3];
      }
  }

  auto stage = [&](int ks, int b) {
    bf16x8 z = {0,0,0,0,0,0,0,0};
    bf16x8 v0 = z, v1 = z;
    if (sp0) { v0 = *(const bf16x8*)(sp0 + ks*32); v1 = *(const bf16x8*)(sp0 + ks*32 + 8); }
    *(bf16x8*)&Alds[b][r0][h0*16]     = v0;
    *(bf16x8*)&Alds[b][r0][h0*16 + 8] = v1;
    if (tid < 2*MT - 256) {
      bf16x8 w0 = z, w1 = z;
      if (sp1) { w0 = *(const bf16x8*)(sp1 + ks*32); w1 = *(const bf16x8*)(sp1 + ks*32 + 8); }
      *(bf16x8*)&Alds[b][r1][h1*16]     = w0;
      *(bf16x8*)&Alds[b][r1][h1*16 + 8] = w1;
    }
  };

  f32x4 bA[8];
  auto loadB = [&](int ks) {
    const float* bp = Bq + (size_t)ks * 32 * NGU;
#pragma unroll
    for (int j = 0; j < 8; ++j)
      bA[j] = __builtin_nontemporal_load((const f32x4*)(bp + (size_t)j * NGU));
  };

  loadB(0);
  stage(0, 0);
  lds_barrier();
  int buf = 0;

  for (int ks = 0; ks < KSTEPS; ++ks) {
    if (ks + 1 < KSTEPS) stage(ks + 1, buf ^ 1);
    bf16x8 bgE, buE, bgO, buO;
#pragma unroll
    for (int j = 0; j < 8; ++j) {
      bgE[j] = (short)f2bf(bA[j][0]); buE[j] = (short)f2bf(bA[j][1]);
      bgO[j] = (short)f2bf(bA[j][2]); buO[j] = (short)f2bf(bA[j][3]);
    }
    if (ks + 1 < KSTEPS) loadB(ks + 1);
#pragma unroll
    for (int m = 0; m < MFR; ++m) {
      bf16x8 a = *(const bf16x8*)&Alds[buf][m*16 + l15][lg*8];
      accgE[m] = __builtin_amdgcn_mfma_f32_16x16x32_bf16(a, bgE, accgE[m], 0, 0, 0);
      accuE[m] = __builtin_amdgcn_mfma_f32_16x16x32_bf16(a, buE, accuE[m], 0, 0, 0);
      accgO[m] = __builtin_amdgcn_mfma_f32_16x16x32_bf16(a, bgO, accgO[m], 0, 0, 0);
      accuO[m] = __builtin_amdgcn_mfma_f32_16x16x32_bf16(a, buO, accuO[m], 0, 0, 0);
    }
    lds_barrier();
    buf ^= 1;
  }

  if (fcE < HDIM) {
#pragma unroll
    for (int m = 0; m < MFR; ++m) {
#pragma unroll
      for (int r = 0; r < 4; ++r) {
        int grow = m0 + m*16 + lg*4 + r;
        if (grow < n_e) {
          float pw = pair_w[segs + grow];
          float gE = fminf(accgE[m][r], 7.f);
          float uE = fminf(fmaxf(accuE[m][r], -7.f), 7.f);
          float avE = (uE + 1.f) * (gE / (1.f + __expf(-1.702f * gE))) * pw;
          float gO = fminf(accgO[m][r], 7.f);
          float uO = fminf(fmaxf(accuO[m][r], -7.f), 7.f);
          float avO = (uO + 1.f) * (gO / (1.f + __expf(-1.702f * gO))) * pw;
          unsigned pk = (unsigned)f2bf(avE) | ((unsigned)f2bf(avO) << 16);
          *(unsigned*)&act[(size_t)(segs + grow) * HDIM + fcE] = pk;
        }
      }
    }
  }
}

// ---------------- down projection: K-split halves, bf16 partials ----------
__global__ __launch_bounds__(256, 3) void k_down(
    const unsigned short* __restrict__ act, const float* __restrict__ dw,
    const int* __restrict__ seg, const int* __restrict__ pair_tok,
    unsigned short* __restrict__ partial)
{
  const int e = blockIdx.z;
  const int mi = blockIdx.y >> 1;
  const int kh = blockIdx.y & 1;
  const int segs = seg[e];
  const int n_e = seg[e+1] - segs;
  const int m0 = mi * MT;
  if (m0 >= n_e) return;
  const int tid = threadIdx.x;
  const int lane = tid & 63;
  const int wid = tid >> 6;
  const int l15 = lane & 15, lg = lane >> 4;
  const int cb = blockIdx.x * 128 + wid * 32;
  const int cE = cb + 2*l15;
  const int colc = min(cE, HDIM - 2);
  const int k0 = kh * (KSH * 32);

  __shared__ unsigned short Alds[2][MT][40];

  unsigned short* po = partial + (size_t)kh * PARTELT;
  const float* Bq = dw + (size_t)e * HDIM * HDIM + colc
                  + (size_t)(k0 + lg * 8) * HDIM;

  const unsigned short* sp0 = nullptr;
  const unsigned short* sp1 = nullptr;
  const int r0 = tid >> 1, h0 = tid & 1;
  const int r1 = (tid + 256) >> 1, h1 = tid & 1;
  if (m0 + r0 < n_e) sp0 = act + (size_t)(segs + m0 + r0) * HDIM + k0 + h0*16;
  if (tid < 2*MT - 256 && m0 + r1 < n_e)
    sp1 = act + (size_t)(segs + m0 + r1) * HDIM + k0 + h1*16;

  f32x4 accE[MFR], accO[MFR];
#pragma unroll
  for (int m = 0; m < MFR; ++m)
#pragma unroll
    for (int r = 0; r < 4; ++r) { accE[m][r] = 0.f; accO[m][r] = 0.f; }

  auto stage = [&](int ks, int b) {
    bf16x8 z = {0,0,0,0,0,0,0,0};
    bf16x8 v0 = z, v1 = z;
    if (sp0) { v0 = *(const bf16x8*)(sp0 + ks*32); v1 = *(const bf16x8*)(sp0 + ks*32 + 8); }
    *(bf16x8*)&Alds[b][r0][h0*16]     = v0;
    *(bf16x8*)&Alds[b][r0][h0*16 + 8] = v1;
    if (tid < 2*MT - 256) {
      bf16x8 w0 = z, w1 = z;
      if (sp1) { w0 = *(const bf16x8*)(sp1 + ks*32); w1 = *(const bf16x8*)(sp1 + ks*32 + 8); }
      *(bf16x8*)&Alds[b][r1][h1*16]     = w0;
      *(bf16x8*)&Alds[b][r1][h1*16 + 8] = w1;
    }
  };

  f32x2 bA[8];
  auto loadB = [&](int ks) {
    const float* bp = Bq + (size_t)ks * 32 * HDIM;
#pragma unroll
    for (int j = 0; j < 8; ++j)
      bA[j] = __builtin_nontemporal_load((const f32x2*)(bp + (size_t)j * HDIM));
  };

  loadB(0);
  stage(0, 0);
  lds_barrier();
  int buf = 0;

  for (int ks = 0; ks < KSH; ++ks) {
    if (ks + 1 < KSH) stage(ks + 1, buf ^ 1);
    bf16x8 bfE, bfO;
#pragma unroll
    for (int j = 0; j < 8; ++j) { bfE[j] = (short)f2bf(bA[j][0]); bfO[j] = (short)f2bf(bA[j][1]); }
    if (ks + 1 < KSH) loadB(ks + 1);
#pragma unroll
    for (int m = 0; m < MFR; ++m) {
      bf16x8 a = *(const bf16x8*)&Alds[buf][m*16 + l15][lg*8];
      accE[m] = __builtin_amdgcn_mfma_f32_16x16x32_bf16(a, bfE, accE[m], 0, 0, 0);
      accO[m] = __builtin_amdgcn_mfma_f32_16x16x32_bf16(a, bfO, accO[m], 0, 0, 0);
    }
    lds_barrier();
    buf ^= 1;
  }

  if (cE < HDIM) {
#pragma unroll
    for (int m = 0; m < MFR; ++m) {
#pragma unroll
      for (int r = 0; r < 4; ++r) {
        int grow = m0 + m*16 + lg*4 + r;
        if (grow < n_e) {
          unsigned pk = (unsigned)f2bf(accE[m][r]) | ((unsigned)f2bf(accO[m][r]) << 16);
          *(unsigned*)&po[(size_t)(segs + grow) * HDIM + cE] = pk;
        }
      }
    }
  }
}

// ---- gather: out[t] = sum over 8 bf16 partial rows + score-weighted bias ----
__global__ __launch_bounds__(256) void k_gather(
    const unsigned short* __restrict__ partial, const int* __restrict__ pair_of,
    const int* __restrict__ top_e, const float* __restrict__ top_w,
    const float* __restrict__ db, float* __restrict__ out)
{
  const int t = blockIdx.x;
  const int tid = threadIdx.x;
  const int p0 = pair_of[t*4+0], p1 = pair_of[t*4+1];
  const int p2 = pair_of[t*4+2], p3 = pair_of[t*4+3];
  const float w0 = top_w[t*4+0], w1 = top_w[t*4+1];
  const float w2 = top_w[t*4+2], w3 = top_w[t*4+3];
  const unsigned short* r[8] = {
    partial + (size_t)p0 * HDIM,           partial + (size_t)p1 * HDIM,
    partial + (size_t)p2 * HDIM,           partial + (size_t)p3 * HDIM,
    partial + PARTELT + (size_t)p0 * HDIM, partial + PARTELT + (size_t)p1 * HDIM,
    partial + PARTELT + (size_t)p2 * HDIM, partial + PARTELT + (size_t)p3 * HDIM };
  const float* b0 = db + (size_t)top_e[t*4+0] * HDIM;
  const float* b1 = db + (size_t)top_e[t*4+1] * HDIM;
  const float* b2 = db + (size_t)top_e[t*4+2] * HDIM;
  const float* b3 = db + (size_t)top_e[t*4+3] * HDIM;
  float* o = out + (size_t)t * HDIM;
  for (int p = tid; p < HDIM/4; p += 256) {
    f32x4 s;
    {
      f32x4 c0 = *(const f32x4*)(b0 + 4*p);
      f32x4 c1 = *(const f32x4*)(b1 + 4*p);
      f32x4 c2 = *(const f32x4*)(b2 + 4*p);
      f32x4 c3 = *(const f32x4*)(b3 + 4*p);
#pragma unroll
      for (int j = 0; j < 4; ++j)
        s[j] = (w0*c0[j] + w1*c1[j]) + (w2*c2[j] + w3*c3[j]);
    }
#pragma unroll
    for (int q = 0; q < 8; ++q) {
      uint2 v = *(const uint2*)(r[q] + 4*p);   // 4 bf16: cols 4p..4p+3
      s[0] += bflo(v.x); s[1] += bfhi(v.x);
      s[2] += bflo(v.y); s[3] += bfhi(v.y);
    }
    *(f32x4*)(o + 4*p) = s;
  }
}

// ---------------- launch ----------------

extern "C" void kernel_launch(void* const* d_in, const int* in_sizes, int n_in,
                              void* d_out, int out_size, void* d_ws, size_t ws_size,
                              hipStream_t stream) {
  const float* x  = (const float*)d_in[0];
  const float* rw = (const float*)d_in[1];
  const float* rb = (const float*)d_in[2];
  const float* gw = (const float*)d_in[3];
  const float* gb = (const float*)d_in[4];
  const float* dw = (const float*)d_in[5];
  const float* db = (const float*)d_in[6];
  float* out = (float*)d_out;

  char* w = (char*)d_ws;
  int*   counts   = (int*)(w);
  int*   seg      = (int*)(w + 64);
  int*   top_e    = (int*)(w + 1024);
  float* top_w    = (float*)(w + 1024 + 8192);
  int*   pair_tok = (int*)(w + 1024 + 16384);
  float* pair_w   = (float*)(w + 1024 + 24576);
  int*   pair_of  = (int*)(w + 1024 + 32768);
  unsigned short* xb  = (unsigned short*)(w + (1 << 20));    // 512 x 2880 bf16
  unsigned short* act = (unsigned short*)(w + (8 << 20));    // 2048 x 2880 bf16
  unsigned short* partial = (unsigned short*)(w + (24ull << 20)); // 2 x 2048 x 2880 bf16

  hipMemsetAsync(counts, 0, NEXP * sizeof(int), stream);
  k_router<<<NTOK, 256, 0, stream>>>(x, rw, rb, counts, top_e, top_w, xb);
  k_fill<<<NEXP, 64, 0, stream>>>(top_e, top_w, counts, seg, pair_tok, pair_w, pair_of);

  dim3 gg(23, 2, NEXP);   // 23 fc tiles x {main, overflow} x experts
  k_gateup<<<gg, 256, 0, stream>>>(xb, gw, gb, seg, pair_tok, pair_w, act);

  dim3 gd(23, 4, NEXP);   // 23 col tiles x {m-tile, K-half} x experts
  k_down<<<gd, 256, 0, stream>>>(act, dw, seg, pair_tok, partial);

  k_gather<<<NTOK, 256, 0, stream>>>(partial, pair_of, top_e, top_w, db, out);
}